// Round 3
// baseline (290.581 us; speedup 1.0000x reference)
//
#include <hip/hip_runtime.h>

#define HH 16
#define DD 64
#define BBATCH 4
#define NSEQ 2048
#define CDIM 1024
#define EPSLN 1e-6f

typedef __bf16 bf16x8 __attribute__((ext_vector_type(8)));
typedef float f32x4 __attribute__((ext_vector_type(4)));
typedef short s16x4 __attribute__((ext_vector_type(4)));
typedef short s16x8 __attribute__((ext_vector_type(8)));
typedef unsigned short u16;

__device__ inline u16 f2b(float f) {  // RNE
  unsigned u = __builtin_bit_cast(unsigned, f);
  u += 0x7fffu + ((u >> 16) & 1u);
  return (u16)(u >> 16);
}
// pack 2 floats -> 2 bf16 (round-half-up), 3 VALU ops via v_perm_b32
#if __has_builtin(__builtin_amdgcn_perm)
__device__ inline unsigned pack2(float a, float b) {
  unsigned ua = __builtin_bit_cast(unsigned, a) + 0x8000u;
  unsigned ub = __builtin_bit_cast(unsigned, b) + 0x8000u;
  return __builtin_amdgcn_perm(ub, ua, 0x07060302u);
}
#else
__device__ inline unsigned pack2(float a, float b) {
  unsigned ua = __builtin_bit_cast(unsigned, a);
  unsigned ub = __builtin_bit_cast(unsigned, b);
  return ((ua + 0x8000u) >> 16) | ((ub + 0x8000u) & 0xffff0000u);
}
#endif
#if __has_builtin(__builtin_amdgcn_exp2f)
#define EXP2(x) __builtin_amdgcn_exp2f(x)
#else
#define EXP2(x) __expf((x)*0.6931471805599453f)
#endif

__device__ inline bf16x8 ld_frag16(const u16* p) {
  s16x8 v = *(const s16x8*)p;
  return __builtin_bit_cast(bf16x8, v);
}
__device__ inline f32x4 mfma16(bf16x8 a, bf16x8 b, f32x4 c) {
  return __builtin_amdgcn_mfma_f32_16x16x32_bf16(a, b, c, 0, 0, 0);
}
// async global->LDS, 16B per lane (lds dst linear in lane: base + lane*16B)
__device__ inline void async16(const u16* g, u16* l) {
  __builtin_amdgcn_global_load_lds(
      (const __attribute__((address_space(1))) void*)g,
      (__attribute__((address_space(3))) void*)l, 16, 0, 0);
}

// ---------------- convert x -> bf16 ----------------
__global__ void cvt_x(const float* __restrict__ x, u16* __restrict__ xb) {
  long i = ((long)blockIdx.x * 256 + threadIdx.x) * 8;
  float4 a = *(const float4*)(x + i);
  float4 b = *(const float4*)(x + i + 4);
  u16 r[8];
  r[0] = f2b(a.x); r[1] = f2b(a.y); r[2] = f2b(a.z); r[3] = f2b(a.w);
  r[4] = f2b(b.x); r[5] = f2b(b.y); r[6] = f2b(b.z); r[7] = f2b(b.w);
  *(s16x8*)(xb + i) = *(s16x8*)r;
}

// ---------------- transpose + convert weight: w [K][N] f32 -> wT [N][K] bf16 ----------------
__global__ void cvt_wT(const float* __restrict__ w, u16* __restrict__ wT, int K, int N) {
  __shared__ float tile[32][33];
  int nt = N / 32;
  int bn = blockIdx.x % nt, bk = blockIdx.x / nt;
  int tx = threadIdx.x % 32, ty = threadIdx.x / 32;
  int k0 = bk * 32, n0 = bn * 32;
  for (int j = 0; j < 4; j++)
    tile[ty + 8 * j][tx] = w[(long)(k0 + ty + 8 * j) * N + n0 + tx];
  __syncthreads();
  for (int j = 0; j < 4; j++)
    wT[(long)(n0 + ty + 8 * j) * K + k0 + tx] = f2b(tile[tx][ty + 8 * j]);
}

// ---------------- GEMM1: qkv = x @ w_qkv + b, fused per-head LN on q/k.
//  LDS rows of 64 u16 = 8 chunks of 16B; stored chunk s of row r holds logical
//  chunk s^(r&7) (swizzle applied on DMA source) -> conflict-free b128 reads.
__launch_bounds__(256, 3)
__global__ void gemm_qkv(const u16* __restrict__ A, const u16* __restrict__ BT,
                         const float* __restrict__ bias,
                         const float* __restrict__ gq, const float* __restrict__ gk,
                         u16* __restrict__ qb, u16* __restrict__ kb, u16* __restrict__ vtb) {
  const int Kd = CDIM;
  __shared__ u16 As[128 * 64];
  __shared__ u16 Bs[128 * 64];
  int t = threadIdx.x;
  int lane = t & 63, wave = t >> 6;
  int ln = lane & 15, quad = lane >> 4;
  int bm = blockIdx.x % 64, bn = blockIdx.x / 64;
  int wm = (wave >> 1) * 64, wn = (wave & 1) * 64;
  int r8 = t >> 3;                      // staged row-within-block 0..31
  int cb = (t & 7) * 8;                 // stored chunk offset (u16)
  int cg = (((t & 7) ^ (r8 & 7)) * 8);  // logical chunk offset for global src
  int swl = ln & 7;                     // read-side swizzle key
  const u16* aB = A + (long)(bm * 128) * Kd + cg;
  const u16* bB = BT + (long)(bn * 128) * Kd + cg;
  f32x4 acc[4][4] = {};
  for (int kt = 0; kt < Kd / 64; kt++) {
    __syncthreads();
#pragma unroll
    for (int c = 0; c < 4; c++) {
      int row = c * 32 + r8;
      async16(aB + (long)row * Kd + kt * 64, As + row * 64 + cb);
      async16(bB + (long)row * Kd + kt * 64, Bs + row * 64 + cb);
    }
    __syncthreads();
#pragma unroll
    for (int kk = 0; kk < 2; kk++) {
      bf16x8 af[4], bfv[4];
#pragma unroll
      for (int mt = 0; mt < 4; mt++)
        af[mt] = ld_frag16(As + (wm + mt * 16 + ln) * 64 + (((kk * 4 + quad) ^ swl) * 8));
#pragma unroll
      for (int nt = 0; nt < 4; nt++)
        bfv[nt] = ld_frag16(Bs + (wn + nt * 16 + ln) * 64 + (((kk * 4 + quad) ^ swl) * 8));
#pragma unroll
      for (int mt = 0; mt < 4; mt++)
#pragma unroll
        for (int nt = 0; nt < 4; nt++)
          acc[mt][nt] = mfma16(af[mt], bfv[nt], acc[mt][nt]);
    }
  }
  // ---- epilogue ----
  int tq = bn >> 3;
  int colbase = bn * 128 + wn;
  int h = (colbase >> 6) & 15;
  int mbase = bm * 128 + wm;
  float bv[4];
#pragma unroll
  for (int nt = 0; nt < 4; nt++) bv[nt] = bias[colbase + nt * 16 + ln];
  if (tq == 2) {
#pragma unroll
    for (int mt = 0; mt < 4; mt++) {
      int m0 = mbase + mt * 16 + quad * 4;
      int b = m0 >> 11, n0 = m0 & 2047;
#pragma unroll
      for (int nt = 0; nt < 4; nt++) {
        int d = nt * 16 + ln;
        u16 pk[4];
#pragma unroll
        for (int r = 0; r < 4; r++) pk[r] = f2b(acc[mt][nt][r] + bv[nt]);
        *(s16x4*)(vtb + ((long)((b * HH + h) * DD + d)) * NSEQ + n0) = *(s16x4*)pk;
      }
    }
  } else {
    const float* g = (tq == 0) ? gq : gk;
    float extra = (tq == 0) ? 0.125f * 1.4426950408889634f : 1.0f;
    u16* dst = (tq == 0) ? qb : kb;
    float gv[4];
#pragma unroll
    for (int nt = 0; nt < 4; nt++) gv[nt] = g[nt * 16 + ln] * extra;
#pragma unroll
    for (int mt = 0; mt < 4; mt++)
#pragma unroll
      for (int r = 0; r < 4; r++) {
        float vv[4];
        float s1 = 0.f, s2 = 0.f;
#pragma unroll
        for (int nt = 0; nt < 4; nt++) {
          vv[nt] = acc[mt][nt][r] + bv[nt];
          s1 += vv[nt];
          s2 += vv[nt] * vv[nt];
        }
#pragma unroll
        for (int m = 1; m < 16; m <<= 1) {
          s1 += __shfl_xor(s1, m);
          s2 += __shfl_xor(s2, m);
        }
        float mu = s1 * (1.0f / 64.0f);
        float var = s2 * (1.0f / 64.0f) - mu * mu;
        float rstd = rsqrtf(var + EPSLN);
        int m = mbase + mt * 16 + quad * 4 + r;
        int b = m >> 11, n = m & 2047;
        long base = ((long)((b * HH + h) * NSEQ + n)) * DD;
#pragma unroll
        for (int nt = 0; nt < 4; nt++)
          dst[base + nt * 16 + ln] = f2b((vv[nt] - mu) * rstd * gv[nt]);
      }
  }
}

// Compute body for one 128-wide K/V tile, 32 q-rows per wave, P handled in
// 32-k quarters ([32q][32k] per wave -> 8 KB total LDS for P).
#define ATTN_TILE_COMPUTE()                                                      \
  _Pragma("unroll")                                                              \
  for (int qt = 0; qt < 4; qt++) {                                               \
    _Pragma("unroll")                                                            \
    for (int ctl = 0; ctl < 2; ctl++) {                                          \
      int ct = qt * 2 + ctl;                                                     \
      const u16* ka = Ks + (ct * 16 + ln) * 64;                                  \
      bf16x8 k0 = ld_frag16(ka + ((quad ^ swl) * 8));                            \
      bf16x8 k1 = ld_frag16(ka + (((quad + 4) ^ swl) * 8));                      \
      int poffc = (ctl * 16 + quad * 4) ^ psw;                                   \
      _Pragma("unroll")                                                          \
      for (int qf = 0; qf < 2; qf++) {                                           \
        f32x4 z = {};                                                            \
        z = mfma16(k0, bq[qf][0], z);                                            \
        z = mfma16(k1, bq[qf][1], z);                                            \
        float e0 = EXP2(z[0]), e1 = EXP2(z[1]), e2 = EXP2(z[2]), e3 = EXP2(z[3]);\
        rs[qf] += (e0 + e1) + (e2 + e3);                                         \
        uint2 pk;                                                                \
        pk.x = pack2(e0, e1);                                                    \
        pk.y = pack2(e2, e3);                                                    \
        *(uint2*)(Pw + (qf * 16 + ln) * 32 + poffc) = pk;                        \
      }                                                                          \
    }                                                                            \
    bf16x8 pA[2];                                                                \
    _Pragma("unroll")                                                            \
    for (int qf = 0; qf < 2; qf++)                                               \
      pA[qf] = ld_frag16(Pw + (qf * 16 + ln) * 32 + ((quad * 8) ^ psw));         \
    _Pragma("unroll")                                                            \
    for (int dt = 0; dt < 4; dt++) {                                             \
      const u16* vrow = Vs + (dt * 16 + ln) * 128;                               \
      bf16x8 vv = ld_frag16(vrow + (((4 * qt + quad) ^ swl) * 8));               \
      __builtin_amdgcn_s_setprio(1);                                             \
      _Pragma("unroll")                                                          \
      for (int qf = 0; qf < 2; qf++)                                             \
        o[qf][dt] = mfma16(pA[qf], vv, o[qf][dt]);                               \
      __builtin_amdgcn_s_setprio(0);                                             \
    }                                                                            \
  }

// ---------------- flash attention v9: occupancy restructure.
//  32 q-rows/wave (128/block), grid 1024 = exactly 4 blocks/CU; P shrunk to
//  [32q][32k]/wave (8 KB) -> LDS 40 KB -> 4 blocks resident, 16 waves/CU
//  (was 2 blocks / 8 waves: the R0-R2 counters showed 25-30% no-issue gap
//  from TLP starvation). K/V staging + T14 named-reg prefetch unchanged.
__launch_bounds__(256, 4)
__global__ void attn(const u16* __restrict__ qb, const u16* __restrict__ kb,
                     const u16* __restrict__ vtb, u16* __restrict__ ob) {
  __shared__ u16 smem[20480];            // 40 KB
  u16* Ks = smem;                        // [128][64]  16 KB
  u16* Vs = smem + 8192;                 // [64][128]  16 KB (V^T: [d][k])
  u16* Pl = smem + 16384;                // 4 waves x [32 q][32 k]  8 KB
  int t = threadIdx.x, lane = t & 63, wave = t >> 6;
  int ln = lane & 15, quad = lane >> 4;
  int g = blockIdx.x;
  int bh = (g & 7) * 8 + ((g >> 3) & 7); // XCD swizzle: 8 bh per XCD
  int qblk = g >> 6;                     // 0..15, 128 q-rows each
  int b = bh >> 4, h = bh & 15;
  const u16* qg = qb + (long)bh * NSEQ * DD;
  const u16* kg = kb + (long)bh * NSEQ * DD;
  const u16* vg = vtb + (long)bh * DD * NSEQ;
  int qrow0 = qblk * 128 + wave * 32;
  bf16x8 bq[2][2];
#pragma unroll
  for (int qf = 0; qf < 2; qf++)
#pragma unroll
    for (int kk = 0; kk < 2; kk++)
      bq[qf][kk] = ld_frag16(qg + (long)(qrow0 + qf * 16 + ln) * DD + kk * 32 + quad * 8);
  f32x4 o[2][4] = {};
  float rs[2] = {0.f, 0.f};
  u16* Pw = Pl + wave * 1024;            // [32 q][32 k]
  int psw = (ln & 3) * 8;                // P column swizzle (u16 units, 4 chunks)
  int swl = ln & 7;                      // K/V read swizzle key
  int cK = (lane & 7) ^ (lane >> 3);     // K staging: logical chunk per lane
  int rV = lane >> 4;                    // V staging: row-within-group

  // per-lane fixed staging addresses (same mapping as the DMA path)
  int lr3 = lane >> 3;
  const u16* kpfB = kg + (long)(wave * 8 + lr3) * DD + cK * 8;
  int cV = (lane & 15) ^ ((wave * 4 + rV) & 7);   // c*16 ≡ 0 (mod 8) -> c-independent
  const u16* vpfB = vg + (long)(wave * 4 + rV) * NSEQ + cV * 8;
  u16* kdst = Ks + wave * 8 * 64 + lane * 8;
  u16* vdst = Vs + wave * 4 * 128 + lane * 8;

  // ---- prologue: stage tile 0 via DMA ----
#pragma unroll
  for (int c = 0; c < 4; c++) {
    int rowb = c * 32 + wave * 8;
    async16(kg + (long)(rowb + lr3) * DD + cK * 8, Ks + rowb * 64 + lane * 8);
  }
#pragma unroll
  for (int c = 0; c < 4; c++) {
    int drow = c * 16 + wave * 4;
    int rv = drow + rV;
    async16(vg + (long)rv * NSEQ + cV * 8, Vs + drow * 128 + lane * 8);
  }
  __syncthreads();

  for (int kv = 0; kv < NSEQ / 128 - 1; kv++) {
    // ---- issue prefetch for tile kv+1 into 8 named VGPR quads ----
    const u16* ks = kpfB + (long)(kv + 1) * 128 * DD;
    const u16* vs = vpfB + (long)(kv + 1) * 128;
    uint4 ka0 = *(const uint4*)(ks);
    uint4 ka1 = *(const uint4*)(ks + 32 * DD);
    uint4 ka2 = *(const uint4*)(ks + 64 * DD);
    uint4 ka3 = *(const uint4*)(ks + 96 * DD);
    uint4 va0 = *(const uint4*)(vs);
    uint4 va1 = *(const uint4*)(vs + (long)16 * NSEQ);
    uint4 va2 = *(const uint4*)(vs + (long)32 * NSEQ);
    uint4 va3 = *(const uint4*)(vs + (long)48 * NSEQ);
    __builtin_amdgcn_sched_barrier(0);   // pin load issue before compute
    // ---- compute on tile kv (reads LDS; load latency hides under it) ----
    ATTN_TILE_COMPUTE();
    // ---- commit prefetched tile to LDS ----
    __syncthreads();                     // all waves done reading LDS(kv)
    *(uint4*)(kdst) = ka0;
    *(uint4*)(kdst + 32 * 64) = ka1;
    *(uint4*)(kdst + 64 * 64) = ka2;
    *(uint4*)(kdst + 96 * 64) = ka3;
    *(uint4*)(vdst) = va0;
    *(uint4*)(vdst + 16 * 128) = va1;
    *(uint4*)(vdst + 32 * 128) = va2;
    *(uint4*)(vdst + 48 * 128) = va3;
    __syncthreads();                     // writes visible before next compute
  }
  // ---- peeled final tile (no prefetch) ----
  ATTN_TILE_COMPUTE();

  // epilogue: normalize and store [B,N,H,D]
#pragma unroll
  for (int qf = 0; qf < 2; qf++) {
    float r2 = rs[qf];
    r2 += __shfl_xor(r2, 16);
    r2 += __shfl_xor(r2, 32);
#pragma unroll
    for (int r = 0; r < 4; r++) {
      float inv = 1.0f / __shfl(r2, quad * 4 + r);
      int n = qrow0 + qf * 16 + quad * 4 + r;
      long base = ((long)(b * NSEQ + n) * HH + h) * DD;
#pragma unroll
      for (int dt = 0; dt < 4; dt++)
        ob[base + dt * 16 + ln] = f2b(o[qf][dt][r] * inv);
    }
  }
}

// ---------------- GEMM2: out = o @ w_proj + b_proj (fp32 out), same swizzle ----------------
__launch_bounds__(256, 3)
__global__ void gemm_proj(const u16* __restrict__ A, const u16* __restrict__ BT,
                          const float* __restrict__ bias, float* __restrict__ out) {
  const int Kd = CDIM;
  __shared__ u16 As[128 * 64];
  __shared__ u16 Bs[128 * 64];
  int t = threadIdx.x;
  int lane = t & 63, wave = t >> 6;
  int ln = lane & 15, quad = lane >> 4;
  int bm = blockIdx.x % 64, bn = blockIdx.x / 64;
  int wm = (wave >> 1) * 64, wn = (wave & 1) * 64;
  int r8 = t >> 3;
  int cb = (t & 7) * 8;
  int cg = (((t & 7) ^ (r8 & 7)) * 8);
  int swl = ln & 7;
  const u16* aB = A + (long)(bm * 128) * Kd + cg;
  const u16* bB = BT + (long)(bn * 128) * Kd + cg;
  f32x4 acc[4][4] = {};
  for (int kt = 0; kt < Kd / 64; kt++) {
    __syncthreads();
#pragma unroll
    for (int c = 0; c < 4; c++) {
      int row = c * 32 + r8;
      async16(aB + (long)row * Kd + kt * 64, As + row * 64 + cb);
      async16(bB + (long)row * Kd + kt * 64, Bs + row * 64 + cb);
    }
    __syncthreads();
#pragma unroll
    for (int kk = 0; kk < 2; kk++) {
      bf16x8 af[4], bfv[4];
#pragma unroll
      for (int mt = 0; mt < 4; mt++)
        af[mt] = ld_frag16(As + (wm + mt * 16 + ln) * 64 + (((kk * 4 + quad) ^ swl) * 8));
#pragma unroll
      for (int nt = 0; nt < 4; nt++)
        bfv[nt] = ld_frag16(Bs + (wn + nt * 16 + ln) * 64 + (((kk * 4 + quad) ^ swl) * 8));
#pragma unroll
      for (int mt = 0; mt < 4; mt++)
#pragma unroll
        for (int nt = 0; nt < 4; nt++)
          acc[mt][nt] = mfma16(af[mt], bfv[nt], acc[mt][nt]);
    }
  }
#pragma unroll
  for (int mt = 0; mt < 4; mt++)
#pragma unroll
    for (int nt = 0; nt < 4; nt++) {
      int col = bn * 128 + wn + nt * 16 + ln;
      float bvx = bias[col];
#pragma unroll
      for (int r = 0; r < 4; r++) {
        int m = bm * 128 + wm + mt * 16 + quad * 4 + r;
        out[(long)m * CDIM + col] = acc[mt][nt][r] + bvx;
      }
    }
}

extern "C" void kernel_launch(void* const* d_in, const int* in_sizes, int n_in,
                              void* d_out, int out_size, void* d_ws, size_t ws_size,
                              hipStream_t stream) {
  const float* x = (const float*)d_in[0];
  const float* w_qkv = (const float*)d_in[1];
  const float* b_qkv = (const float*)d_in[2];
  const float* g_q = (const float*)d_in[3];
  const float* g_k = (const float*)d_in[4];
  const float* w_proj = (const float*)d_in[5];
  const float* b_proj = (const float*)d_in[6];
  float* out = (float*)d_out;

  char* ws = (char*)d_ws;
  const size_t MB = 1024 * 1024;
  u16* xb = (u16*)ws;                 // 16 MB, reused as o after gemm_qkv
  u16* wqkvT = (u16*)(ws + 16 * MB);  // 6 MB
  u16* wprojT = (u16*)(ws + 22 * MB); // 2 MB
  u16* qb = (u16*)(ws + 24 * MB);     // 16 MB
  u16* kb = (u16*)(ws + 40 * MB);     // 16 MB
  u16* vtb = (u16*)(ws + 56 * MB);    // 16 MB  (V transposed [B,H,D,N])
  u16* ob = xb;

  cvt_x<<<4096, 256, 0, stream>>>(x, xb);
  cvt_wT<<<(1024 / 32) * (3072 / 32), 256, 0, stream>>>(w_qkv, wqkvT, CDIM, 3 * CDIM);
  cvt_wT<<<(1024 / 32) * (1024 / 32), 256, 0, stream>>>(w_proj, wprojT, CDIM, CDIM);
  gemm_qkv<<<64 * 24, 256, 0, stream>>>(xb, wqkvT, b_qkv, g_q, g_k, qb, kb, vtb);
  attn<<<1024, 256, 0, stream>>>(qb, kb, vtb, ob);
  gemm_proj<<<64 * 8, 256, 0, stream>>>(ob, wprojT, b_proj, out);
}

// Round 5
// 261.976 us; speedup vs baseline: 1.1092x; 1.1092x over previous
//
#include <hip/hip_runtime.h>

#define HH 16
#define DD 64
#define BBATCH 4
#define NSEQ 2048
#define CDIM 1024
#define EPSLN 1e-6f

typedef __bf16 bf16x8 __attribute__((ext_vector_type(8)));
typedef float f32x4 __attribute__((ext_vector_type(4)));
typedef float f32x16 __attribute__((ext_vector_type(16)));
typedef short s16x4 __attribute__((ext_vector_type(4)));
typedef short s16x8 __attribute__((ext_vector_type(8)));
typedef unsigned short u16;

__device__ inline u16 f2b(float f) {  // RNE
  unsigned u = __builtin_bit_cast(unsigned, f);
  u += 0x7fffu + ((u >> 16) & 1u);
  return (u16)(u >> 16);
}
// pack 2 floats -> 2 bf16 (round-half-up), 3 VALU ops via v_perm_b32
#if __has_builtin(__builtin_amdgcn_perm)
__device__ inline unsigned pack2(float a, float b) {
  unsigned ua = __builtin_bit_cast(unsigned, a) + 0x8000u;
  unsigned ub = __builtin_bit_cast(unsigned, b) + 0x8000u;
  return __builtin_amdgcn_perm(ub, ua, 0x07060302u);
}
#else
__device__ inline unsigned pack2(float a, float b) {
  unsigned ua = __builtin_bit_cast(unsigned, a);
  unsigned ub = __builtin_bit_cast(unsigned, b);
  return ((ua + 0x8000u) >> 16) | ((ub + 0x8000u) & 0xffff0000u);
}
#endif
#if __has_builtin(__builtin_amdgcn_exp2f)
#define EXP2(x) __builtin_amdgcn_exp2f(x)
#else
#define EXP2(x) __expf((x)*0.6931471805599453f)
#endif

__device__ inline bf16x8 ld_frag16(const u16* p) {
  s16x8 v = *(const s16x8*)p;
  return __builtin_bit_cast(bf16x8, v);
}
__device__ inline f32x4 mfma16(bf16x8 a, bf16x8 b, f32x4 c) {
  return __builtin_amdgcn_mfma_f32_16x16x32_bf16(a, b, c, 0, 0, 0);
}
__device__ inline f32x16 mfma32(bf16x8 a, bf16x8 b, f32x16 c) {
  return __builtin_amdgcn_mfma_f32_32x32x16_bf16(a, b, c, 0, 0, 0);
}
// async global->LDS, 16B per lane (lds dst linear in lane: base + lane*16B)
__device__ inline void async16(const u16* g, u16* l) {
  __builtin_amdgcn_global_load_lds(
      (const __attribute__((address_space(1))) void*)g,
      (__attribute__((address_space(3))) void*)l, 16, 0, 0);
}

// ---------------- convert x -> bf16 ----------------
__global__ void cvt_x(const float* __restrict__ x, u16* __restrict__ xb) {
  long i = ((long)blockIdx.x * 256 + threadIdx.x) * 8;
  float4 a = *(const float4*)(x + i);
  float4 b = *(const float4*)(x + i + 4);
  u16 r[8];
  r[0] = f2b(a.x); r[1] = f2b(a.y); r[2] = f2b(a.z); r[3] = f2b(a.w);
  r[4] = f2b(b.x); r[5] = f2b(b.y); r[6] = f2b(b.z); r[7] = f2b(b.w);
  *(s16x8*)(xb + i) = *(s16x8*)r;
}

// ---------------- transpose + convert weight: w [K][N] f32 -> wT [N][K] bf16 ----------------
__global__ void cvt_wT(const float* __restrict__ w, u16* __restrict__ wT, int K, int N) {
  __shared__ float tile[32][33];
  int nt = N / 32;
  int bn = blockIdx.x % nt, bk = blockIdx.x / nt;
  int tx = threadIdx.x % 32, ty = threadIdx.x / 32;
  int k0 = bk * 32, n0 = bn * 32;
  for (int j = 0; j < 4; j++)
    tile[ty + 8 * j][tx] = w[(long)(k0 + ty + 8 * j) * N + n0 + tx];
  __syncthreads();
  for (int j = 0; j < 4; j++)
    wT[(long)(n0 + ty + 8 * j) * K + k0 + tx] = f2b(tile[tx][ty + 8 * j]);
}

// ---------------- GEMM1: qkv = x @ w_qkv + b, fused per-head LN on q/k.
__launch_bounds__(256, 3)
__global__ void gemm_qkv(const u16* __restrict__ A, const u16* __restrict__ BT,
                         const float* __restrict__ bias,
                         const float* __restrict__ gq, const float* __restrict__ gk,
                         u16* __restrict__ qb, u16* __restrict__ kb, u16* __restrict__ vtb) {
  const int Kd = CDIM;
  __shared__ u16 As[128 * 64];
  __shared__ u16 Bs[128 * 64];
  int t = threadIdx.x;
  int lane = t & 63, wave = t >> 6;
  int ln = lane & 15, quad = lane >> 4;
  int bm = blockIdx.x % 64, bn = blockIdx.x / 64;
  int wm = (wave >> 1) * 64, wn = (wave & 1) * 64;
  int r8 = t >> 3;                      // staged row-within-block 0..31
  int cb = (t & 7) * 8;                 // stored chunk offset (u16)
  int cg = (((t & 7) ^ (r8 & 7)) * 8);  // logical chunk offset for global src
  int swl = ln & 7;                     // read-side swizzle key
  const u16* aB = A + (long)(bm * 128) * Kd + cg;
  const u16* bB = BT + (long)(bn * 128) * Kd + cg;
  f32x4 acc[4][4] = {};
  for (int kt = 0; kt < Kd / 64; kt++) {
    __syncthreads();
#pragma unroll
    for (int c = 0; c < 4; c++) {
      int row = c * 32 + r8;
      async16(aB + (long)row * Kd + kt * 64, As + row * 64 + cb);
      async16(bB + (long)row * Kd + kt * 64, Bs + row * 64 + cb);
    }
    __syncthreads();
#pragma unroll
    for (int kk = 0; kk < 2; kk++) {
      bf16x8 af[4], bfv[4];
#pragma unroll
      for (int mt = 0; mt < 4; mt++)
        af[mt] = ld_frag16(As + (wm + mt * 16 + ln) * 64 + (((kk * 4 + quad) ^ swl) * 8));
#pragma unroll
      for (int nt = 0; nt < 4; nt++)
        bfv[nt] = ld_frag16(Bs + (wn + nt * 16 + ln) * 64 + (((kk * 4 + quad) ^ swl) * 8));
#pragma unroll
      for (int mt = 0; mt < 4; mt++)
#pragma unroll
        for (int nt = 0; nt < 4; nt++)
          acc[mt][nt] = mfma16(af[mt], bfv[nt], acc[mt][nt]);
    }
  }
  // ---- epilogue ----
  int tq = bn >> 3;
  int colbase = bn * 128 + wn;
  int h = (colbase >> 6) & 15;
  int mbase = bm * 128 + wm;
  float bv[4];
#pragma unroll
  for (int nt = 0; nt < 4; nt++) bv[nt] = bias[colbase + nt * 16 + ln];
  if (tq == 2) {
#pragma unroll
    for (int mt = 0; mt < 4; mt++) {
      int m0 = mbase + mt * 16 + quad * 4;
      int b = m0 >> 11, n0 = m0 & 2047;
#pragma unroll
      for (int nt = 0; nt < 4; nt++) {
        int d = nt * 16 + ln;
        u16 pk[4];
#pragma unroll
        for (int r = 0; r < 4; r++) pk[r] = f2b(acc[mt][nt][r] + bv[nt]);
        *(s16x4*)(vtb + ((long)((b * HH + h) * DD + d)) * NSEQ + n0) = *(s16x4*)pk;
      }
    }
  } else {
    const float* g = (tq == 0) ? gq : gk;
    float extra = (tq == 0) ? 0.125f * 1.4426950408889634f : 1.0f;
    u16* dst = (tq == 0) ? qb : kb;
    float gv[4];
#pragma unroll
    for (int nt = 0; nt < 4; nt++) gv[nt] = g[nt * 16 + ln] * extra;
#pragma unroll
    for (int mt = 0; mt < 4; mt++)
#pragma unroll
      for (int r = 0; r < 4; r++) {
        float vv[4];
        float s1 = 0.f, s2 = 0.f;
#pragma unroll
        for (int nt = 0; nt < 4; nt++) {
          vv[nt] = acc[mt][nt][r] + bv[nt];
          s1 += vv[nt];
          s2 += vv[nt] * vv[nt];
        }
#pragma unroll
        for (int m = 1; m < 16; m <<= 1) {
          s1 += __shfl_xor(s1, m);
          s2 += __shfl_xor(s2, m);
        }
        float mu = s1 * (1.0f / 64.0f);
        float var = s2 * (1.0f / 64.0f) - mu * mu;
        float rstd = rsqrtf(var + EPSLN);
        int m = mbase + mt * 16 + quad * 4 + r;
        int b = m >> 11, n = m & 2047;
        long base = ((long)((b * HH + h) * NSEQ + n)) * DD;
#pragma unroll
        for (int nt = 0; nt < 4; nt++)
          dst[base + nt * 16 + ln] = f2b((vv[nt] - mu) * rstd * gv[nt]);
      }
  }
}

// Compute body for one 128-wide K/V tile, 32x32x16 MFMA, P fully in-register.
// P cross-half exchange done with __shfl_xor(.,32) + hl-select (bisect: the
// permlane32_swap builtin and v_cvt_pk asm from v10 are replaced with the
// R0-R3-proven pack2 + shfl primitives; structure otherwise identical).
// Lane (l,hl) z regs hold S^T[kvpos=(r&3)+8(r>>2)+4hl][q=l] per 32-row block.
// pb0 needs k0..15: hl=0 {own k0..3, partner k4..7}; hl=1 {partner k8..11, own k12..15}.
#define ATTN_TILE_COMPUTE()                                                       \
  _Pragma("unroll")                                                               \
  for (int kbq = 0; kbq < 4; kbq++) {                                             \
    const u16* kaB = Ks + (kbq * 32 + l) * 64;                                    \
    bf16x8 ak0 = ld_frag16(kaB + (((0 + hl) ^ sw3) * 8));                         \
    bf16x8 ak1 = ld_frag16(kaB + (((2 + hl) ^ sw3) * 8));                         \
    bf16x8 ak2 = ld_frag16(kaB + (((4 + hl) ^ sw3) * 8));                         \
    bf16x8 ak3 = ld_frag16(kaB + (((6 + hl) ^ sw3) * 8));                         \
    const u16* vaB = Vs + l * 128;                                                \
    bf16x8 av00 = ld_frag16(vaB + (((kbq * 4 + 0 + hl) ^ sw3) * 8));              \
    bf16x8 av01 = ld_frag16(vaB + (((kbq * 4 + 2 + hl) ^ sw3) * 8));              \
    bf16x8 av10 = ld_frag16(vaB + 32 * 128 + (((kbq * 4 + 0 + hl) ^ sw3) * 8));   \
    bf16x8 av11 = ld_frag16(vaB + 32 * 128 + (((kbq * 4 + 2 + hl) ^ sw3) * 8));   \
    _Pragma("unroll")                                                             \
    for (int qc = 0; qc < 2; qc++) {                                              \
      f32x16 z = {};                                                              \
      z = mfma32(ak0, bq[qc][0], z);                                              \
      z = mfma32(ak1, bq[qc][1], z);                                              \
      z = mfma32(ak2, bq[qc][2], z);                                              \
      z = mfma32(ak3, bq[qc][3], z);                                              \
      float e0 = EXP2(z[0]), e1 = EXP2(z[1]), e2 = EXP2(z[2]), e3 = EXP2(z[3]);   \
      float e4 = EXP2(z[4]), e5 = EXP2(z[5]), e6 = EXP2(z[6]), e7 = EXP2(z[7]);   \
      float e8 = EXP2(z[8]), e9 = EXP2(z[9]), e10 = EXP2(z[10]), e11 = EXP2(z[11]);\
      float e12 = EXP2(z[12]), e13 = EXP2(z[13]), e14 = EXP2(z[14]), e15 = EXP2(z[15]);\
      rs[qc] += (((e0 + e1) + (e2 + e3)) + ((e4 + e5) + (e6 + e7))) +             \
                (((e8 + e9) + (e10 + e11)) + ((e12 + e13) + (e14 + e15)));        \
      unsigned A0 = pack2(e0, e1), A1 = pack2(e2, e3);                            \
      unsigned B0 = pack2(e4, e5), B1 = pack2(e6, e7);                            \
      unsigned C0 = pack2(e8, e9), C1 = pack2(e10, e11);                          \
      unsigned D0 = pack2(e12, e13), D1 = pack2(e14, e15);                        \
      unsigned xA0 = __shfl_xor(A0, 32), xA1 = __shfl_xor(A1, 32);                \
      unsigned xB0 = __shfl_xor(B0, 32), xB1 = __shfl_xor(B1, 32);                \
      unsigned xC0 = __shfl_xor(C0, 32), xC1 = __shfl_xor(C1, 32);                \
      unsigned xD0 = __shfl_xor(D0, 32), xD1 = __shfl_xor(D1, 32);                \
      uint4 wa;                                                                   \
      wa.x = hl ? xB0 : A0;                                                       \
      wa.y = hl ? xB1 : A1;                                                       \
      wa.z = hl ? B0 : xA0;                                                       \
      wa.w = hl ? B1 : xA1;                                                       \
      bf16x8 pb0 = __builtin_bit_cast(bf16x8, wa);                                \
      uint4 wb;                                                                   \
      wb.x = hl ? xD0 : C0;                                                       \
      wb.y = hl ? xD1 : C1;                                                       \
      wb.z = hl ? D0 : xC0;                                                       \
      wb.w = hl ? D1 : xC1;                                                       \
      bf16x8 pb1 = __builtin_bit_cast(bf16x8, wb);                                \
      __builtin_amdgcn_s_setprio(1);                                              \
      o[0][qc] = mfma32(av00, pb0, o[0][qc]);                                     \
      o[0][qc] = mfma32(av01, pb1, o[0][qc]);                                     \
      o[1][qc] = mfma32(av10, pb0, o[1][qc]);                                     \
      o[1][qc] = mfma32(av11, pb1, o[1][qc]);                                     \
      __builtin_amdgcn_s_setprio(0);                                              \
    }                                                                             \
  }

// ---------------- flash attention v11: 32x32 swapped-QK^T, in-register P,
//  conservative primitives (pack2 + shfl_xor). 64 q/wave as 2 q-frags of 32.
//  K/V LDS layouts, swizzles, T14 named-reg prefetch and barrier structure
//  identical to v8/R2 (3x harness-verified). LDS = 32 KB.
__launch_bounds__(256, 2)
__global__ void attn(const u16* __restrict__ qb, const u16* __restrict__ kbuf,
                     const u16* __restrict__ vtb, u16* __restrict__ ob) {
  __shared__ u16 smem[16384];            // 32 KB
  u16* Ks = smem;                        // [128][64]  16 KB
  u16* Vs = smem + 8192;                 // [64][128]  16 KB (V^T: [d][k])
  int t = threadIdx.x, lane = t & 63, wave = t >> 6;
  int l = lane & 31, hl = lane >> 5;     // 32x32 operand coords
  int sw3 = l & 7;                       // LDS read swizzle key (row&7)
  int g = blockIdx.x;
  int bh = (g & 7) * 8 + ((g >> 3) & 7); // XCD swizzle: 8 bh per XCD
  int qblk = (g >> 6) & 7;               // 0..7, 256 q-rows each
  int b = bh >> 4, hh = bh & 15;
  const u16* qg = qb + (long)bh * NSEQ * DD;
  const u16* kg = kbuf + (long)bh * NSEQ * DD;
  const u16* vg = vtb + (long)bh * DD * NSEQ;
  int qrow0 = qblk * 256 + wave * 64;
  // Q fragments: B-operand of 32x32x16, lane (l,hl) = Q[q=qc*32+l][d=ds*16+hl*8..+7]
  bf16x8 bq[2][4];
#pragma unroll
  for (int qc = 0; qc < 2; qc++)
#pragma unroll
    for (int ds = 0; ds < 4; ds++)
      bq[qc][ds] = ld_frag16(qg + (long)(qrow0 + qc * 32 + l) * DD + ds * 16 + hl * 8);
  f32x16 o[2][2] = {};                   // o^T: [db][qc], d=rows, q=cols
  float rs[2] = {0.f, 0.f};
  int cK = (lane & 7) ^ (lane >> 3);     // K staging: logical chunk per lane
  int rV = lane >> 4;                    // V staging: row-within-group

  // per-lane fixed staging addresses (same mapping as the DMA path)
  int lr3 = lane >> 3;
  const u16* kpfB = kg + (long)(wave * 8 + lr3) * DD + cK * 8;
  int cV = (lane & 15) ^ ((wave * 4 + rV) & 7);   // c*16 ≡ 0 (mod 8) -> c-independent
  const u16* vpfB = vg + (long)(wave * 4 + rV) * NSEQ + cV * 8;
  u16* kdst = Ks + wave * 8 * 64 + lane * 8;
  u16* vdst = Vs + wave * 4 * 128 + lane * 8;

  // ---- prologue: stage tile 0 via DMA ----
#pragma unroll
  for (int c = 0; c < 4; c++) {
    int rowb = c * 32 + wave * 8;
    async16(kg + (long)(rowb + lr3) * DD + cK * 8, Ks + rowb * 64 + lane * 8);
  }
#pragma unroll
  for (int c = 0; c < 4; c++) {
    int drow = c * 16 + wave * 4;
    int rv = drow + rV;
    async16(vg + (long)rv * NSEQ + cV * 8, Vs + drow * 128 + lane * 8);
  }
  __syncthreads();

  for (int kv = 0; kv < NSEQ / 128 - 1; kv++) {
    // ---- issue prefetch for tile kv+1 into 8 named VGPR quads ----
    const u16* ks = kpfB + (long)(kv + 1) * 128 * DD;
    const u16* vs = vpfB + (long)(kv + 1) * 128;
    uint4 ka0 = *(const uint4*)(ks);
    uint4 ka1 = *(const uint4*)(ks + 32 * DD);
    uint4 ka2 = *(const uint4*)(ks + 64 * DD);
    uint4 ka3 = *(const uint4*)(ks + 96 * DD);
    uint4 va0 = *(const uint4*)(vs);
    uint4 va1 = *(const uint4*)(vs + (long)16 * NSEQ);
    uint4 va2 = *(const uint4*)(vs + (long)32 * NSEQ);
    uint4 va3 = *(const uint4*)(vs + (long)48 * NSEQ);
    __builtin_amdgcn_sched_barrier(0);   // pin load issue before compute
    // ---- compute on tile kv (reads LDS; load latency hides under it) ----
    ATTN_TILE_COMPUTE();
    // ---- commit prefetched tile to LDS ----
    __syncthreads();                     // all waves done reading LDS(kv)
    *(uint4*)(kdst) = ka0;
    *(uint4*)(kdst + 32 * 64) = ka1;
    *(uint4*)(kdst + 64 * 64) = ka2;
    *(uint4*)(kdst + 96 * 64) = ka3;
    *(uint4*)(vdst) = va0;
    *(uint4*)(vdst + 16 * 128) = va1;
    *(uint4*)(vdst + 32 * 128) = va2;
    *(uint4*)(vdst + 48 * 128) = va3;
    __syncthreads();                     // writes visible before next compute
  }
  // ---- peeled final tile (no prefetch) ----
  ATTN_TILE_COMPUTE();

  // epilogue: rs halves combine (lane l and l+32 hold complementary k-subsets),
  // then normalize o^T and store [B,N,H,D]. Lane (l,hl): q=qc*32+l,
  // d = db*32 + 8*rq + 4*hl + j for reg rq*4+j.
#pragma unroll
  for (int qc = 0; qc < 2; qc++) {
    float r2 = rs[qc] + __shfl_xor(rs[qc], 32);
    float inv = 1.0f / r2;
    int n = qrow0 + qc * 32 + l;
    long base = ((long)(b * NSEQ + n) * HH + hh) * DD;
#pragma unroll
    for (int db = 0; db < 2; db++)
#pragma unroll
      for (int rq = 0; rq < 4; rq++) {
        u16 pk[4];
#pragma unroll
        for (int j = 0; j < 4; j++) pk[j] = f2b(o[db][qc][rq * 4 + j] * inv);
        *(s16x4*)(ob + base + db * 32 + rq * 8 + hl * 4) = *(s16x4*)pk;
      }
  }
}

// ---------------- GEMM2: out = o @ w_proj + b_proj (fp32 out), same swizzle ----------------
__launch_bounds__(256, 3)
__global__ void gemm_proj(const u16* __restrict__ A, const u16* __restrict__ BT,
                          const float* __restrict__ bias, float* __restrict__ out) {
  const int Kd = CDIM;
  __shared__ u16 As[128 * 64];
  __shared__ u16 Bs[128 * 64];
  int t = threadIdx.x;
  int lane = t & 63, wave = t >> 6;
  int ln = lane & 15, quad = lane >> 4;
  int bm = blockIdx.x % 64, bn = blockIdx.x / 64;
  int wm = (wave >> 1) * 64, wn = (wave & 1) * 64;
  int r8 = t >> 3;
  int cb = (t & 7) * 8;
  int cg = (((t & 7) ^ (r8 & 7)) * 8);
  int swl = ln & 7;
  const u16* aB = A + (long)(bm * 128) * Kd + cg;
  const u16* bB = BT + (long)(bn * 128) * Kd + cg;
  f32x4 acc[4][4] = {};
  for (int kt = 0; kt < Kd / 64; kt++) {
    __syncthreads();
#pragma unroll
    for (int c = 0; c < 4; c++) {
      int row = c * 32 + r8;
      async16(aB + (long)row * Kd + kt * 64, As + row * 64 + cb);
      async16(bB + (long)row * Kd + kt * 64, Bs + row * 64 + cb);
    }
    __syncthreads();
#pragma unroll
    for (int kk = 0; kk < 2; kk++) {
      bf16x8 af[4], bfv[4];
#pragma unroll
      for (int mt = 0; mt < 4; mt++)
        af[mt] = ld_frag16(As + (wm + mt * 16 + ln) * 64 + (((kk * 4 + quad) ^ swl) * 8));
#pragma unroll
      for (int nt = 0; nt < 4; nt++)
        bfv[nt] = ld_frag16(Bs + (wn + nt * 16 + ln) * 64 + (((kk * 4 + quad) ^ swl) * 8));
#pragma unroll
      for (int mt = 0; mt < 4; mt++)
#pragma unroll
        for (int nt = 0; nt < 4; nt++)
          acc[mt][nt] = mfma16(af[mt], bfv[nt], acc[mt][nt]);
    }
  }
#pragma unroll
  for (int mt = 0; mt < 4; mt++)
#pragma unroll
    for (int nt = 0; nt < 4; nt++) {
      int col = bn * 128 + wn + nt * 16 + ln;
      float bvx = bias[col];
#pragma unroll
      for (int r = 0; r < 4; r++) {
        int m = bm * 128 + wm + mt * 16 + quad * 4 + r;
        out[(long)m * CDIM + col] = acc[mt][nt][r] + bvx;
      }
    }
}

extern "C" void kernel_launch(void* const* d_in, const int* in_sizes, int n_in,
                              void* d_out, int out_size, void* d_ws, size_t ws_size,
                              hipStream_t stream) {
  const float* x = (const float*)d_in[0];
  const float* w_qkv = (const float*)d_in[1];
  const float* b_qkv = (const float*)d_in[2];
  const float* g_q = (const float*)d_in[3];
  const float* g_k = (const float*)d_in[4];
  const float* w_proj = (const float*)d_in[5];
  const float* b_proj = (const float*)d_in[6];
  float* out = (float*)d_out;

  char* ws = (char*)d_ws;
  const size_t MB = 1024 * 1024;
  u16* xb = (u16*)ws;                 // 16 MB, reused as o after gemm_qkv
  u16* wqkvT = (u16*)(ws + 16 * MB);  // 6 MB
  u16* wprojT = (u16*)(ws + 22 * MB); // 2 MB
  u16* qb = (u16*)(ws + 24 * MB);     // 16 MB
  u16* kb = (u16*)(ws + 40 * MB);     // 16 MB
  u16* vtb = (u16*)(ws + 56 * MB);    // 16 MB  (V transposed [B,H,D,N])
  u16* ob = xb;

  cvt_x<<<4096, 256, 0, stream>>>(x, xb);
  cvt_wT<<<(1024 / 32) * (3072 / 32), 256, 0, stream>>>(w_qkv, wqkvT, CDIM, 3 * CDIM);
  cvt_wT<<<(1024 / 32) * (1024 / 32), 256, 0, stream>>>(w_proj, wprojT, CDIM, CDIM);
  gemm_qkv<<<64 * 24, 256, 0, stream>>>(xb, wqkvT, b_qkv, g_q, g_k, qb, kb, vtb);
  attn<<<512, 256, 0, stream>>>(qb, kb, vtb, ob);
  gemm_proj<<<64 * 8, 256, 0, stream>>>(ob, wprojT, b_proj, out);
}